// Round 1
// baseline (229.598 us; speedup 1.0000x reference)
//
#include <hip/hip_runtime.h>
#include <cstdint>
#include <cstddef>

#define L_SEQ 2048
#define E_DIM 512
#define B_SZ 2
#define M_ROWS (B_SZ * L_SEQ)      // 4096
#define WIN 64
#define WTOT 129                   // 2*WIN+1
#define SCALE_QK 0.044194173824159216f  // 1/sqrt(512)

typedef __attribute__((ext_vector_type(8))) short short8;
typedef __attribute__((ext_vector_type(4))) float floatx4;

// ---------------- fp32 -> bf16 (RNE) conversion ----------------
__device__ __forceinline__ unsigned short f2bf(float f) {
    unsigned int u = __float_as_uint(f);
    u += 0x7FFFu + ((u >> 16) & 1u);
    return (unsigned short)(u >> 16);
}

// one float4 per thread; x: 524288 float4s, each W: 65536 float4s
__global__ __launch_bounds__(256) void cvt_kernel(
    const float* __restrict__ x, const float* __restrict__ wq,
    const float* __restrict__ wk, const float* __restrict__ wv,
    unsigned short* __restrict__ xb, unsigned short* __restrict__ wb)
{
    long i = (long)blockIdx.x * 256 + threadIdx.x;   // 0 .. 720895
    const float* src;
    unsigned short* dst;
    long off;
    if (i < 524288) {
        src = x; dst = xb; off = i;
    } else {
        long j = i - 524288;
        int w = (int)(j >> 16);          // 0..2
        off = j & 65535;
        src = (w == 0) ? wq : ((w == 1) ? wk : wv);
        dst = wb + (long)w * 262144;
    }
    float4 f = ((const float4*)src)[off];
    ushort4 o;
    o.x = f2bf(f.x); o.y = f2bf(f.y); o.z = f2bf(f.z); o.w = f2bf(f.w);
    ((ushort4*)dst)[off] = o;
}

// ---------------- QKV projection GEMM (bf16 MFMA, fp32 acc) ----------------
// C[m,n] = sum_k X[m,k] * W[n,k] + bias[n]   (W already in (N,K) = B^T layout)
// 64x64 tile per block, 4 waves, each wave: 16 rows x 64 cols via 4 MFMAs.
__global__ __launch_bounds__(256) void qkv_gemm(
    const unsigned short* __restrict__ xb,   // 4096 x 512 bf16
    const unsigned short* __restrict__ wb,   // 3 x (512 x 512) bf16
    const float* __restrict__ bq, const float* __restrict__ bk, const float* __restrict__ bv,
    float* __restrict__ q, float* __restrict__ k, float* __restrict__ v)
{
    __shared__ __align__(16) unsigned short As[64 * 32];
    __shared__ __align__(16) unsigned short Bs[64 * 32];

    const int t  = threadIdx.x;
    const int wv_ = t >> 6;          // wave 0..3
    const int l  = t & 63;           // lane
    const int m0 = blockIdx.x * 64;
    const int n0 = blockIdx.y * 64;
    const int z  = blockIdx.z;       // 0:q 1:k 2:v

    const unsigned short* W = wb + (size_t)z * (512 * 512);
    const float* bias = (z == 0) ? bq : ((z == 1) ? bk : bv);
    float* out = (z == 0) ? q : ((z == 1) ? k : v);

    floatx4 acc[4] = {};

    const int lr = t >> 2;            // load row 0..63
    const int lc = (t & 3) * 8;       // load col 0,8,16,24 (bf16 units)
    const int fr = (l & 15);          // fragment m/n
    const int fk = (l >> 4) * 8;      // fragment k offset

    for (int kk = 0; kk < 512; kk += 32) {
        __syncthreads();
        *(uint4*)&As[lr * 32 + lc] = *(const uint4*)&xb[(size_t)(m0 + lr) * 512 + kk + lc];
        *(uint4*)&Bs[lr * 32 + lc] = *(const uint4*)&W [(size_t)(n0 + lr) * 512 + kk + lc];
        __syncthreads();
        short8 a = *(const short8*)&As[(wv_ * 16 + fr) * 32 + fk];
#pragma unroll
        for (int j = 0; j < 4; j++) {
            short8 b = *(const short8*)&Bs[(j * 16 + fr) * 32 + fk];
            acc[j] = __builtin_amdgcn_mfma_f32_16x16x32_bf16(a, b, acc[j], 0, 0, 0);
        }
    }

    // epilogue: C/D layout col = lane&15, row = (lane>>4)*4 + reg
    const int crow = m0 + wv_ * 16 + (l >> 4) * 4;
#pragma unroll
    for (int j = 0; j < 4; j++) {
        int col = n0 + j * 16 + (l & 15);
        float bval = bias[col];
#pragma unroll
        for (int r = 0; r < 4; r++) {
            out[(size_t)(crow + r) * 512 + col] = acc[j][r] + bval;
        }
    }
}

// ---------------- Local attention (fp32, LDS-staged windows) ----------------
#define TQ 8
#define ROWS (TQ + 2 * WIN)    // 136
#define ECH 64                 // e-chunk
#define NCH (E_DIM / ECH)      // 8

__global__ __launch_bounds__(256) void attn_kernel(
    const float* __restrict__ q, const float* __restrict__ k,
    const float* __restrict__ v, float* __restrict__ out)
{
    __shared__ __align__(16) float kc[ROWS * ECH];   // 34816 B, reused for v
    __shared__ float S[TQ * 132];                    // 4224 B

    const int t  = threadIdx.x;
    const int b  = blockIdx.y;
    const int q0 = blockIdx.x * TQ;

    const float* qp = q + (size_t)b * L_SEQ * E_DIM;
    const float* kp = k + (size_t)b * L_SEQ * E_DIM;
    const float* vp = v + (size_t)b * L_SEQ * E_DIM;
    float* op = out + (size_t)b * L_SEQ * E_DIM;

    for (int i = t; i < TQ * 132; i += 256) S[i] = 0.f;

    const int oct  = t >> 3, lane8 = t & 7;
    const int qi   = oct >> 2, part = oct & 3;      // 4 octets per query
    const int wj0  = part * 33;
    const int wj1  = (part == 3) ? WTOT : (wj0 + 33);
    const int qrow = q0 + qi;

    // ---- phase A: scores ----
    for (int ec = 0; ec < NCH; ec++) {
        __syncthreads();
        for (int i = t; i < ROWS * (ECH / 4); i += 256) {   // 2176 float4
            int row = i >> 4, c4 = i & 15;
            int jr = q0 - WIN + row;
            float4 val = make_float4(0.f, 0.f, 0.f, 0.f);
            if (jr >= 0 && jr < L_SEQ)
                val = *(const float4*)&kp[(size_t)jr * E_DIM + ec * ECH + c4 * 4];
            *(float4*)&kc[row * ECH + c4 * 4] = val;
        }
        __syncthreads();
        float4 qa = *(const float4*)&qp[(size_t)qrow * E_DIM + ec * ECH + lane8 * 4];
        float4 qb = *(const float4*)&qp[(size_t)qrow * E_DIM + ec * ECH + 32 + lane8 * 4];
        for (int wj = wj0; wj < wj1; wj++) {
            int jrg = qrow + wj - WIN;
            if (jrg < 0 || jrg >= L_SEQ) continue;
            int rl = qi + wj;
            float4 ka = *(const float4*)&kc[rl * ECH + lane8 * 4];
            float4 kb = *(const float4*)&kc[rl * ECH + 32 + lane8 * 4];
            float d = qa.x * ka.x + qa.y * ka.y + qa.z * ka.z + qa.w * ka.w
                    + qb.x * kb.x + qb.y * kb.y + qb.z * kb.z + qb.w * kb.w;
            d += __shfl_xor(d, 1);
            d += __shfl_xor(d, 2);
            d += __shfl_xor(d, 4);
            if (lane8 == 0) S[qi * 132 + wj] += d;
        }
    }
    __syncthreads();

    // ---- phase B: softmax (32 lanes per query row) ----
    {
        const int team = t >> 5, l32 = t & 31;
        float m = -1e30f;
        for (int wj = l32; wj < WTOT; wj += 32) {
            int jrg = q0 + team + wj - WIN;
            float s = (jrg >= 0 && jrg < L_SEQ) ? S[team * 132 + wj] * SCALE_QK : -1e30f;
            S[team * 132 + wj] = s;
            m = fmaxf(m, s);
        }
#pragma unroll
        for (int d = 16; d >= 1; d >>= 1) m = fmaxf(m, __shfl_xor(m, d));
        float sum = 0.f;
        for (int wj = l32; wj < WTOT; wj += 32) {
            float e = __expf(S[team * 132 + wj] - m);
            S[team * 132 + wj] = e;
            sum += e;
        }
#pragma unroll
        for (int d = 16; d >= 1; d >>= 1) sum += __shfl_xor(sum, d);
        float inv = 1.f / sum;
        for (int wj = l32; wj < WTOT; wj += 32) S[team * 132 + wj] *= inv;
    }

    // ---- phase C: out = P @ V ----
    const int cqi = t >> 5;        // query 0..7
    const int c2  = t & 31;        // float2 column within chunk
    float* vc = kc;
    for (int ec = 0; ec < NCH; ec++) {
        __syncthreads();
        for (int i = t; i < ROWS * (ECH / 4); i += 256) {
            int row = i >> 4, c4 = i & 15;
            int jr = q0 - WIN + row;
            float4 val = make_float4(0.f, 0.f, 0.f, 0.f);
            if (jr >= 0 && jr < L_SEQ)
                val = *(const float4*)&vp[(size_t)jr * E_DIM + ec * ECH + c4 * 4];
            *(float4*)&vc[row * ECH + c4 * 4] = val;
        }
        __syncthreads();
        float2 acc = make_float2(0.f, 0.f);
#pragma unroll 4
        for (int wj = 0; wj < WTOT; wj++) {
            float p = S[cqi * 132 + wj];
            float2 vv = *(const float2*)&vc[(cqi + wj) * ECH + c2 * 2];
            acc.x += p * vv.x;
            acc.y += p * vv.y;
        }
        *(float2*)&op[(size_t)(q0 + cqi) * E_DIM + ec * ECH + c2 * 2] = acc;
    }
}

// ---------------- launch ----------------
extern "C" void kernel_launch(void* const* d_in, const int* in_sizes, int n_in,
                              void* d_out, int out_size, void* d_ws, size_t ws_size,
                              hipStream_t stream)
{
    const float* x  = (const float*)d_in[0];
    const float* Wq = (const float*)d_in[1];
    const float* bq = (const float*)d_in[2];
    const float* Wk = (const float*)d_in[3];
    const float* bk = (const float*)d_in[4];
    const float* Wv = (const float*)d_in[5];
    const float* bv = (const float*)d_in[6];
    float* out = (float*)d_out;

    char* ws = (char*)d_ws;
    float* q = (float*)(ws);                       // 4096*512*4 = 8 MB
    float* k = (float*)(ws + 8388608);             // 8 MB
    float* v = (float*)(ws + 16777216);            // 8 MB
    unsigned short* xb = (unsigned short*)(ws + 25165824);   // 4 MB (bf16 x)
    unsigned short* wb = (unsigned short*)(ws + 29360128);   // 1.5 MB (bf16 Wq|Wk|Wv)

    cvt_kernel<<<2816, 256, 0, stream>>>(x, Wq, Wk, Wv, xb, wb);
    qkv_gemm<<<dim3(64, 8, 3), 256, 0, stream>>>(xb, wb, bq, bk, bv, q, k, v);
    attn_kernel<<<dim3(L_SEQ / TQ, B_SZ), 256, 0, stream>>>(q, k, v, out);
}

// Round 2
// 137.290 us; speedup vs baseline: 1.6724x; 1.6724x over previous
//
#include <hip/hip_runtime.h>
#include <cstdint>
#include <cstddef>

#define L_SEQ 2048
#define E_DIM 512
#define B_SZ 2
#define WIN 64
#define SCALE_QK 0.044194173824159216f  // 1/sqrt(512)

typedef __attribute__((ext_vector_type(8))) short short8;
typedef __attribute__((ext_vector_type(4))) float floatx4;

__device__ __forceinline__ unsigned short f2bf(float f) {
    unsigned int u = __float_as_uint(f);
    u += 0x7FFFu + ((u >> 16) & 1u);
    return (unsigned short)(u >> 16);
}

// ---------------- fp32 -> bf16 conversion of x, Wq, Wk, Wv ----------------
__global__ __launch_bounds__(256) void cvt_kernel(
    const float* __restrict__ x, const float* __restrict__ wq,
    const float* __restrict__ wk, const float* __restrict__ wv,
    unsigned short* __restrict__ xb, unsigned short* __restrict__ wb)
{
    long i = (long)blockIdx.x * 256 + threadIdx.x;   // 0 .. 720895
    const float* src;
    unsigned short* dst;
    long off;
    if (i < 524288) {
        src = x; dst = xb; off = i;
    } else {
        long j = i - 524288;
        int w = (int)(j >> 16);
        off = j & 65535;
        src = (w == 0) ? wq : ((w == 1) ? wk : wv);
        dst = wb + (long)w * 262144;
    }
    float4 f = ((const float4*)src)[off];
    ushort4 o;
    o.x = f2bf(f.x); o.y = f2bf(f.y); o.z = f2bf(f.z); o.w = f2bf(f.w);
    ((ushort4*)dst)[off] = o;
}

// ---------------- QKV projection: 128x128 tile bf16 MFMA ----------------
// C[m,n] = sum_k X[m,k] W[n,k] + bias[n].  Outputs bf16.
// z==0 -> q[m][n], z==1 -> k[m][n], z==2 -> vT[n][m] (transposed for PV MFMA).
#define BLD 40   // padded LDS row (bf16 units): 80 B = 20 dwords -> 2-way only
__global__ __launch_bounds__(256) void qkv_gemm(
    const unsigned short* __restrict__ xb,   // 4096 x 512
    const unsigned short* __restrict__ wb,   // 3 x (512 x 512), (N,K)
    const float* __restrict__ bq, const float* __restrict__ bk, const float* __restrict__ bv,
    unsigned short* __restrict__ q, unsigned short* __restrict__ k,
    unsigned short* __restrict__ vt)
{
    __shared__ __align__(16) unsigned short As[128 * BLD];
    __shared__ __align__(16) unsigned short Bs[128 * BLD];

    const int t = threadIdx.x;
    const int w = t >> 6, l = t & 63;
    const int m0 = blockIdx.x * 128, n0 = blockIdx.y * 128, z = blockIdx.z;
    const unsigned short* W = wb + (size_t)z * 262144;
    const float* bias = (z == 0) ? bq : ((z == 1) ? bk : bv);

    floatx4 acc[4][4] = {};
    const int wm = (w >> 1) * 64, wn = (w & 1) * 64;
    const int fr = l & 15, fk = (l >> 4) * 8;

    const int srow = t >> 2, scol = (t & 3) * 8;   // staging: 16B per thread per shot

    for (int kk = 0; kk < 512; kk += 32) {
#pragma unroll
        for (int s = 0; s < 2; s++) {
            int row = srow + s * 64;
            *(uint4*)&As[row * BLD + scol] = *(const uint4*)&xb[(size_t)(m0 + row) * 512 + kk + scol];
            *(uint4*)&Bs[row * BLD + scol] = *(const uint4*)&W [(size_t)(n0 + row) * 512 + kk + scol];
        }
        __syncthreads();
        short8 a[4], b[4];
#pragma unroll
        for (int i = 0; i < 4; i++) a[i] = *(const short8*)&As[(wm + i * 16 + fr) * BLD + fk];
#pragma unroll
        for (int j = 0; j < 4; j++) b[j] = *(const short8*)&Bs[(wn + j * 16 + fr) * BLD + fk];
#pragma unroll
        for (int i = 0; i < 4; i++)
#pragma unroll
            for (int j = 0; j < 4; j++)
                acc[i][j] = __builtin_amdgcn_mfma_f32_16x16x32_bf16(a[i], b[j], acc[i][j], 0, 0, 0);
        __syncthreads();
    }

    // epilogue: C/D layout col = lane&15, row = (lane>>4)*4 + reg
    const int fq4 = (l >> 4) * 4;
    if (z < 2) {
        unsigned short* out = (z == 0) ? q : k;
#pragma unroll
        for (int j = 0; j < 4; j++) {
            int col = n0 + wn + j * 16 + fr;
            float bval = bias[col];
#pragma unroll
            for (int i = 0; i < 4; i++) {
                int row = m0 + wm + i * 16 + fq4;
#pragma unroll
                for (int r = 0; r < 4; r++)
                    out[(size_t)(row + r) * 512 + col] = f2bf(acc[i][j][r] + bval);
            }
        }
    } else {
#pragma unroll
        for (int j = 0; j < 4; j++) {
            int col = n0 + wn + j * 16 + fr;
            float bval = bias[col];
#pragma unroll
            for (int i = 0; i < 4; i++) {
                int row = m0 + wm + i * 16 + fq4;
                ushort4 pk;
                pk.x = f2bf(acc[i][j][0] + bval);
                pk.y = f2bf(acc[i][j][1] + bval);
                pk.z = f2bf(acc[i][j][2] + bval);
                pk.w = f2bf(acc[i][j][3] + bval);
                *(ushort4*)&vt[(size_t)col * 4096 + row] = pk;   // vT[e][token]
            }
        }
    }
}

// ---------------- Local attention via MFMA ----------------
// Per block: 16 queries. Window rows: 144 (R0 = Q0-64 .. +143).
// Phase A: S[16x144] = Q @ K_win^T (bf16 MFMA, fp32 acc in regs)
// Phase B: mask+scale -> LDS softmax -> P bf16 in LDS (A-operand layout), K-pad to 160
// Phase C: out[16x512] = P @ V_win using vT (B rows = e-cols), e-chunks of 128
#define TQ 16
#define RW 144
#define KLD 72      // K/Q LDS row stride (bf16): 36 dw -> 2-way
#define PLD 168     // P/Vt LDS row stride (bf16): 84 dw -> 2-way
// LDS map (bytes): [0,20736) K_lds | [20736,23040) Q_lds | [23040,32512) S fp32
//                  [43008,48384) P_lds | phase C: [0,43008) Vt_lds
#define SMEM_BYTES 48384

__global__ __launch_bounds__(256) void attn_kernel(
    const unsigned short* __restrict__ qb, const unsigned short* __restrict__ kb,
    const unsigned short* __restrict__ vt, float* __restrict__ out)
{
    __shared__ __align__(16) char smem[SMEM_BYTES];
    unsigned short* Kl = (unsigned short*)(smem);
    unsigned short* Ql = (unsigned short*)(smem + 20736);
    float*          Sl = (float*)(smem + 23040);
    unsigned short* Pl = (unsigned short*)(smem + 43008);
    unsigned short* Vl = (unsigned short*)(smem);

    const int t = threadIdx.x;
    const int w = t >> 6, l = t & 63;
    const int fr = l & 15, fq = l >> 4, fk = fq * 8;
    const int b = blockIdx.y;
    const int Q0 = blockIdx.x * TQ;
    const int R0 = Q0 - WIN;

    const unsigned short* qp = qb + (size_t)b * L_SEQ * E_DIM;
    const unsigned short* kp = kb + (size_t)b * L_SEQ * E_DIM;
    float* op = out + (size_t)b * L_SEQ * E_DIM;

    // ---- phase A: scores. wave w owns n-tiles {w, w+4, w+8(<9)} ----
    floatx4 acc[3] = {};
    const int ntiles = (w == 0) ? 3 : 2;

    for (int kc = 0; kc < 512; kc += 64) {
        for (int i = t; i < 1152; i += 256) {          // K: 144 rows x 64 cols / 8
            int r = i >> 3, c8 = (i & 7) * 8;
            int gr = R0 + r;
            uint4 val = make_uint4(0, 0, 0, 0);
            if (gr >= 0 && gr < L_SEQ)
                val = *(const uint4*)&kp[(size_t)gr * 512 + kc + c8];
            *(uint4*)&Kl[r * KLD + c8] = val;
        }
        if (t < 128) {                                  // Q: 16 rows x 64 cols / 8
            int qr = t >> 3, c8 = (t & 7) * 8;
            *(uint4*)&Ql[qr * KLD + c8] = *(const uint4*)&qp[(size_t)(Q0 + qr) * 512 + kc + c8];
        }
        __syncthreads();
#pragma unroll
        for (int kk = 0; kk < 64; kk += 32) {
            short8 a = *(const short8*)&Ql[fr * KLD + kk + fk];
#pragma unroll
            for (int it = 0; it < 3; it++) {
                if (it < ntiles) {
                    int tile = w + it * 4;
                    short8 bf = *(const short8*)&Kl[(tile * 16 + fr) * KLD + kk + fk];
                    acc[it] = __builtin_amdgcn_mfma_f32_16x16x32_bf16(a, bf, acc[it], 0, 0, 0);
                }
            }
        }
        __syncthreads();
    }

    // write masked+scaled scores to S
#pragma unroll
    for (int it = 0; it < 3; it++) {
        int tile = w + it * 4;
        if (tile < 9) {
            int j = tile * 16 + fr;
            int gr = R0 + j;
#pragma unroll
            for (int r = 0; r < 4; r++) {
                int qq = fq * 4 + r;
                bool valid = (j >= qq) && (j <= qq + 128) && (gr >= 0) && (gr < L_SEQ);
                Sl[qq * 148 + j] = valid ? acc[it][r] * SCALE_QK : -1e30f;
            }
        }
    }
    __syncthreads();

    // ---- phase B: softmax (16 lanes per query row), P -> bf16 LDS ----
    {
        const int row = t >> 4, l16 = t & 15;
        float* Sr = Sl + row * 148;
        float m = -1e30f;
#pragma unroll
        for (int jj = 0; jj < 9; jj++) m = fmaxf(m, Sr[l16 + jj * 16]);
#pragma unroll
        for (int d = 8; d >= 1; d >>= 1) m = fmaxf(m, __shfl_xor(m, d));
        float e[9], sum = 0.f;
#pragma unroll
        for (int jj = 0; jj < 9; jj++) { e[jj] = __expf(Sr[l16 + jj * 16] - m); sum += e[jj]; }
#pragma unroll
        for (int d = 8; d >= 1; d >>= 1) sum += __shfl_xor(sum, d);
        float inv = 1.f / sum;
#pragma unroll
        for (int jj = 0; jj < 9; jj++) Pl[row * PLD + l16 + jj * 16] = f2bf(e[jj] * inv);
        Pl[row * PLD + 144 + l16] = 0;   // zero K-pad cols 144..159
    }
    __syncthreads();

    // ---- phase C: out = P @ V via vT. e-chunks of 128, wave w -> e-tiles 2w,2w+1 ----
    for (int ec = 0; ec < 512; ec += 128) {
        for (int i = t; i < 2560; i += 256) {          // 128 e x 160 r / 8
            int e_ = i / 20, r8 = (i - e_ * 20) * 8;
            int gr0 = R0 + r8;
            const unsigned short* src = vt + (size_t)(ec + e_) * 4096 + (size_t)b * L_SEQ;
            uint4 val;
            if (gr0 >= 0 && gr0 + 7 < L_SEQ) {
                val = *(const uint4*)&src[gr0];
            } else {
                unsigned short tmp[8];
#pragma unroll
                for (int x = 0; x < 8; x++) {
                    int g = gr0 + x; g = g < 0 ? 0 : (g > L_SEQ - 1 ? L_SEQ - 1 : g);
                    tmp[x] = src[g];
                }
                val = *(uint4*)tmp;
            }
            *(uint4*)&Vl[e_ * PLD + r8] = val;
        }
        __syncthreads();
        floatx4 oa[2] = {};
#pragma unroll
        for (int ks = 0; ks < 5; ks++) {
            short8 a = *(const short8*)&Pl[fr * PLD + ks * 32 + fk];
#pragma unroll
            for (int et = 0; et < 2; et++) {
                short8 bf = *(const short8*)&Vl[((2 * w + et) * 16 + fr) * PLD + ks * 32 + fk];
                oa[et] = __builtin_amdgcn_mfma_f32_16x16x32_bf16(a, bf, oa[et], 0, 0, 0);
            }
        }
#pragma unroll
        for (int et = 0; et < 2; et++) {
            int ecol = ec + (2 * w + et) * 16 + fr;
#pragma unroll
            for (int r = 0; r < 4; r++)
                op[(size_t)(Q0 + fq * 4 + r) * 512 + ecol] = oa[et][r];
        }
        __syncthreads();
    }
}

// ---------------- launch ----------------
extern "C" void kernel_launch(void* const* d_in, const int* in_sizes, int n_in,
                              void* d_out, int out_size, void* d_ws, size_t ws_size,
                              hipStream_t stream)
{
    const float* x  = (const float*)d_in[0];
    const float* Wq = (const float*)d_in[1];
    const float* bq = (const float*)d_in[2];
    const float* Wk = (const float*)d_in[3];
    const float* bk = (const float*)d_in[4];
    const float* Wv = (const float*)d_in[5];
    const float* bv = (const float*)d_in[6];
    float* out = (float*)d_out;

    char* ws = (char*)d_ws;
    unsigned short* qb = (unsigned short*)(ws);                  // 4 MB bf16 q
    unsigned short* kb = (unsigned short*)(ws + 4194304);        // 4 MB bf16 k
    unsigned short* vt = (unsigned short*)(ws + 8388608);        // 4 MB bf16 v^T
    unsigned short* xb = (unsigned short*)(ws + 12582912);       // 4 MB bf16 x
    unsigned short* wb = (unsigned short*)(ws + 16777216);       // 1.5 MB bf16 W

    cvt_kernel<<<2816, 256, 0, stream>>>(x, Wq, Wk, Wv, xb, wb);
    qkv_gemm<<<dim3(32, 4, 3), 256, 0, stream>>>(xb, wb, bq, bk, bv, qb, kb, vt);
    attn_kernel<<<dim3(L_SEQ / TQ, B_SZ), 256, 0, stream>>>(qb, kb, vt, out);
}

// Round 3
// 117.340 us; speedup vs baseline: 1.9567x; 1.1700x over previous
//
#include <hip/hip_runtime.h>
#include <cstdint>
#include <cstddef>

#define L_SEQ 2048
#define E_DIM 512
#define B_SZ 2
#define WIN 64
#define SCALE_QK 0.044194173824159216f  // 1/sqrt(512)

typedef __attribute__((ext_vector_type(8))) short short8;
typedef __attribute__((ext_vector_type(4))) float floatx4;

__device__ __forceinline__ unsigned short f2bf(float f) {
    unsigned int u = __float_as_uint(f);
    u += 0x7FFFu + ((u >> 16) & 1u);
    return (unsigned short)(u >> 16);
}

// ---------------- fp32 -> bf16 conversion of x, Wq, Wk, Wv ----------------
__global__ __launch_bounds__(256) void cvt_kernel(
    const float* __restrict__ x, const float* __restrict__ wq,
    const float* __restrict__ wk, const float* __restrict__ wv,
    unsigned short* __restrict__ xb, unsigned short* __restrict__ wb)
{
    long i = (long)blockIdx.x * 256 + threadIdx.x;   // 0 .. 720895
    const float* src;
    unsigned short* dst;
    long off;
    if (i < 524288) {
        src = x; dst = xb; off = i;
    } else {
        long j = i - 524288;
        int w = (int)(j >> 16);
        off = j & 65535;
        src = (w == 0) ? wq : ((w == 1) ? wk : wv);
        dst = wb + (long)w * 262144;
    }
    float4 f = ((const float4*)src)[off];
    ushort4 o;
    o.x = f2bf(f.x); o.y = f2bf(f.y); o.z = f2bf(f.z); o.w = f2bf(f.w);
    ((ushort4*)dst)[off] = o;
}

// ---------------- QKV projection: 128x128 tile bf16 MFMA ----------------
// C[m,n] = sum_k X[m,k] W[n,k] + bias[n].  Outputs bf16, coalesced via LDS transpose.
// z==0 -> q[m][n], z==1 -> k[m][n], z==2 -> vT[n][m] (token-contiguous rows).
#define BLD 40    // staged-tile LDS row (bf16): 2-way conflicts only
#define TLD 136   // epilogue transpose-tile row (bf16): 272 B, 16 B-aligned
__global__ __launch_bounds__(256) void qkv_gemm(
    const unsigned short* __restrict__ xb,   // 4096 x 512
    const unsigned short* __restrict__ wb,   // 3 x (512 x 512), (N,K)
    const float* __restrict__ bq, const float* __restrict__ bk, const float* __restrict__ bv,
    unsigned short* __restrict__ q, unsigned short* __restrict__ k,
    unsigned short* __restrict__ vt)
{
    __shared__ __align__(16) char smem[35840];
    unsigned short* As = (unsigned short*)smem;            // 128*40*2 = 10240 B
    unsigned short* Bs = (unsigned short*)(smem + 10240);  // 10240 B
    unsigned short* Tl = (unsigned short*)smem;            // 128*136*2 = 34816 B (aliases)

    const int t = threadIdx.x;
    const int w = t >> 6, l = t & 63;
    const int m0 = blockIdx.x * 128, n0 = blockIdx.y * 128, z = blockIdx.z;
    const unsigned short* W = wb + (size_t)z * 262144;
    const float* bias = (z == 0) ? bq : ((z == 1) ? bk : bv);

    floatx4 acc[4][4] = {};
    const int wm = (w >> 1) * 64, wn = (w & 1) * 64;
    const int fr = l & 15, fq = l >> 4, fk = fq * 8;

    const int srow = t >> 2, scol = (t & 3) * 8;

    for (int kk = 0; kk < 512; kk += 32) {
#pragma unroll
        for (int s = 0; s < 2; s++) {
            int row = srow + s * 64;
            *(uint4*)&As[row * BLD + scol] = *(const uint4*)&xb[(size_t)(m0 + row) * 512 + kk + scol];
            *(uint4*)&Bs[row * BLD + scol] = *(const uint4*)&W [(size_t)(n0 + row) * 512 + kk + scol];
        }
        __syncthreads();
        short8 a[4], b[4];
#pragma unroll
        for (int i = 0; i < 4; i++) a[i] = *(const short8*)&As[(wm + i * 16 + fr) * BLD + fk];
#pragma unroll
        for (int j = 0; j < 4; j++) b[j] = *(const short8*)&Bs[(wn + j * 16 + fr) * BLD + fk];
#pragma unroll
        for (int i = 0; i < 4; i++)
#pragma unroll
            for (int j = 0; j < 4; j++)
                acc[i][j] = __builtin_amdgcn_mfma_f32_16x16x32_bf16(a[i], b[j], acc[i][j], 0, 0, 0);
        __syncthreads();
    }

    // epilogue: frags (C/D: col=lane&15, row=(lane>>4)*4+reg) -> LDS tile -> coalesced stores
    float bv_[4];
#pragma unroll
    for (int j = 0; j < 4; j++) bv_[j] = bias[n0 + wn + j * 16 + fr];

    if (z < 2) {
#pragma unroll
        for (int i = 0; i < 4; i++)
#pragma unroll
            for (int j = 0; j < 4; j++)
#pragma unroll
                for (int r = 0; r < 4; r++)
                    Tl[(wm + i * 16 + fq * 4 + r) * TLD + wn + j * 16 + fr] =
                        f2bf(acc[i][j][r] + bv_[j]);
    } else {
#pragma unroll
        for (int i = 0; i < 4; i++)
#pragma unroll
            for (int j = 0; j < 4; j++)
#pragma unroll
                for (int r = 0; r < 4; r++)
                    Tl[(wn + j * 16 + fr) * TLD + wm + i * 16 + fq * 4 + r] =
                        f2bf(acc[i][j][r] + bv_[j]);
    }
    __syncthreads();

    const int tl = t >> 1;
    unsigned short* out = (z == 0) ? q : ((z == 1) ? k : vt);
#pragma unroll
    for (int s = 0; s < 8; s++) {
        int c = (t & 1) * 64 + s * 8;
        uint4 val = *(const uint4*)&Tl[tl * TLD + c];
        if (z < 2)
            *(uint4*)&out[(size_t)(m0 + tl) * 512 + n0 + c] = val;
        else
            *(uint4*)&out[(size_t)(n0 + tl) * 4096 + m0 + c] = val;
    }
}

// ---------------- scores: S[16x16] per one-wave block, direct frag loads ----------------
// grid (128 Qtiles, 9 ntiles, 2 b), 64 threads. S fp32 [4096][160], cols 0..143 written.
__global__ __launch_bounds__(64) void scores_kernel(
    const unsigned short* __restrict__ qb, const unsigned short* __restrict__ kb,
    float* __restrict__ S)
{
    const int l = threadIdx.x;
    const int fr = l & 15, fq = l >> 4;
    const int Q0 = blockIdx.x * 16;
    const int nt = blockIdx.y;
    const int b  = blockIdx.z;
    const int R0 = Q0 - WIN;
    const int tok = R0 + nt * 16 + fr;
    const bool kvalid = (tok >= 0) && (tok < L_SEQ);

    const unsigned short* qrow = qb + (size_t)(b * L_SEQ + Q0 + fr) * 512 + fq * 8;
    const unsigned short* krow = kb + (size_t)(b * L_SEQ) * 512 + (size_t)tok * 512 + fq * 8;

    floatx4 acc = {};
#pragma unroll
    for (int ks = 0; ks < 16; ks++) {
        short8 a = *(const short8*)(qrow + ks * 32);
        short8 bfr = {};
        if (kvalid) bfr = *(const short8*)(krow + ks * 32);
        acc = __builtin_amdgcn_mfma_f32_16x16x32_bf16(a, bfr, acc, 0, 0, 0);
    }

    const int jg = nt * 16 + fr;
    float* Srow = S + (size_t)(b * L_SEQ + Q0) * 160 + jg;
#pragma unroll
    for (int r = 0; r < 4; r++) {
        int qq = fq * 4 + r;
        bool valid = (jg >= qq) && (jg <= qq + 128) && kvalid;
        Srow[(size_t)qq * 160] = valid ? acc[r] * SCALE_QK : -1e30f;
    }
}

// ---------------- softmax: one wave per row -> P bf16 [4096][160] ----------------
__global__ __launch_bounds__(256) void softmax_kernel(
    const float* __restrict__ S, unsigned short* __restrict__ P)
{
    const int t = threadIdx.x;
    const int row = blockIdx.x * 4 + (t >> 6);
    const int l = t & 63;
    const float* Sr = S + (size_t)row * 160;
    float s1 = Sr[l], s2 = Sr[64 + l];
    float s3 = (l < 16) ? Sr[128 + l] : -1e30f;
    float m = fmaxf(fmaxf(s1, s2), s3);
#pragma unroll
    for (int d = 32; d >= 1; d >>= 1) m = fmaxf(m, __shfl_xor(m, d));
    float e1 = __expf(s1 - m), e2 = __expf(s2 - m);
    float e3 = (l < 16) ? __expf(s3 - m) : 0.f;
    float sum = e1 + e2 + e3;
#pragma unroll
    for (int d = 32; d >= 1; d >>= 1) sum += __shfl_xor(sum, d);
    float inv = 1.f / sum;
    unsigned short* Pr = P + (size_t)row * 160;
    Pr[l] = f2bf(e1 * inv);
    Pr[64 + l] = f2bf(e2 * inv);
    if (l < 16) Pr[128 + l] = f2bf(e3 * inv);
    else if (l < 32) Pr[128 + l] = 0;   // zero K-pad cols 144..159
}

// ---------------- pv: out[16q x 32e] per one-wave block ----------------
// grid (128 Qtiles, 16 e-pairs, 2 b), 64 threads. P A-frags + vT B-frags direct from global.
__global__ __launch_bounds__(64) void pv_kernel(
    const unsigned short* __restrict__ P, const unsigned short* __restrict__ vt,
    float* __restrict__ out)
{
    const int l = threadIdx.x;
    const int fr = l & 15, fq = l >> 4;
    const int Q0 = blockIdx.x * 16;
    const int EC = blockIdx.y * 32;
    const int b  = blockIdx.z;
    const int R0 = Q0 - WIN;

    const unsigned short* Prow = P + (size_t)(b * L_SEQ + Q0 + fr) * 160 + fq * 8;

    floatx4 oa[2] = {};
#pragma unroll
    for (int ks = 0; ks < 5; ks++) {
        short8 a = *(const short8*)(Prow + ks * 32);
        int tok0 = R0 + ks * 32 + fq * 8;                 // mod-8 aligned granule
        bool tv = (tok0 >= 0) && (tok0 < L_SEQ);
#pragma unroll
        for (int et = 0; et < 2; et++) {
            short8 bfr = {};
            if (tv) bfr = *(const short8*)&vt[(size_t)(EC + et * 16 + fr) * 4096 + b * L_SEQ + tok0];
            oa[et] = __builtin_amdgcn_mfma_f32_16x16x32_bf16(a, bfr, oa[et], 0, 0, 0);
        }
    }

    float* op = out + (size_t)b * L_SEQ * E_DIM;
#pragma unroll
    for (int et = 0; et < 2; et++)
#pragma unroll
        for (int r = 0; r < 4; r++)
            op[(size_t)(Q0 + fq * 4 + r) * 512 + EC + et * 16 + fr] = oa[et][r];
}

// ---------------- launch ----------------
extern "C" void kernel_launch(void* const* d_in, const int* in_sizes, int n_in,
                              void* d_out, int out_size, void* d_ws, size_t ws_size,
                              hipStream_t stream)
{
    const float* x  = (const float*)d_in[0];
    const float* Wq = (const float*)d_in[1];
    const float* bq = (const float*)d_in[2];
    const float* Wk = (const float*)d_in[3];
    const float* bk = (const float*)d_in[4];
    const float* Wv = (const float*)d_in[5];
    const float* bv = (const float*)d_in[6];
    float* out = (float*)d_out;

    char* ws = (char*)d_ws;
    unsigned short* qb = (unsigned short*)(ws);                  // 4 MB bf16 q
    unsigned short* kb = (unsigned short*)(ws + 4194304);        // 4 MB bf16 k
    unsigned short* vt = (unsigned short*)(ws + 8388608);        // 4 MB bf16 v^T [e][tok]
    unsigned short* xb = (unsigned short*)(ws + 12582912);       // 4 MB bf16 x
    unsigned short* wb = (unsigned short*)(ws + 16777216);       // 1.5 MB bf16 W
    float*          S  = (float*)(ws + 18350080);                // 2.62 MB fp32 [4096][160]
    unsigned short* P  = (unsigned short*)(ws + 20971520);       // 1.31 MB bf16 [4096][160]

    cvt_kernel<<<2816, 256, 0, stream>>>(x, Wq, Wk, Wv, xb, wb);
    qkv_gemm<<<dim3(32, 4, 3), 256, 0, stream>>>(xb, wb, bq, bk, bv, qb, kb, vt);
    scores_kernel<<<dim3(128, 9, 2), 64, 0, stream>>>(qb, kb, S);
    softmax_kernel<<<1024, 256, 0, stream>>>(S, P);
    pv_kernel<<<dim3(128, 16, 2), 64, 0, stream>>>(P, vt, out);
}

// Round 4
// 116.416 us; speedup vs baseline: 1.9722x; 1.0079x over previous
//
#include <hip/hip_runtime.h>
#include <cstdint>
#include <cstddef>

#define L_SEQ 2048
#define E_DIM 512
#define B_SZ 2
#define WIN 64
#define SCALE_QK 0.044194173824159216f  // 1/sqrt(512)

typedef __attribute__((ext_vector_type(8))) short short8;
typedef __attribute__((ext_vector_type(4))) float floatx4;

__device__ __forceinline__ unsigned short f2bf(float f) {
    unsigned int u = __float_as_uint(f);
    u += 0x7FFFu + ((u >> 16) & 1u);
    return (unsigned short)(u >> 16);
}

__device__ __forceinline__ void gld16(const void* g, void* l) {
    __builtin_amdgcn_global_load_lds(
        (const __attribute__((address_space(1))) void*)g,
        (__attribute__((address_space(3))) void*)l, 16, 0, 0);
}

// ---------------- fp32 -> bf16 conversion of x, Wq, Wk, Wv ----------------
__global__ __launch_bounds__(256) void cvt_kernel(
    const float* __restrict__ x, const float* __restrict__ wq,
    const float* __restrict__ wk, const float* __restrict__ wv,
    unsigned short* __restrict__ xb, unsigned short* __restrict__ wb)
{
    long i = (long)blockIdx.x * 256 + threadIdx.x;   // 0 .. 720895
    const float* src;
    unsigned short* dst;
    long off;
    if (i < 524288) {
        src = x; dst = xb; off = i;
    } else {
        long j = i - 524288;
        int w = (int)(j >> 16);
        off = j & 65535;
        src = (w == 0) ? wq : ((w == 1) ? wk : wv);
        dst = wb + (long)w * 262144;
    }
    float4 f = ((const float4*)src)[off];
    ushort4 o;
    o.x = f2bf(f.x); o.y = f2bf(f.y); o.z = f2bf(f.z); o.w = f2bf(f.w);
    ((ushort4*)dst)[off] = o;
}

// ---------------- QKV projection: 128x128 tile bf16 MFMA, global_load_lds ----------------
// C[m,n] = sum_k X[m,k] W[n,k] + bias[n].  Outputs bf16, coalesced via LDS transpose.
// z==0 -> q[m][n], z==1 -> k[m][n], z==2 -> vT[n][m] (token-contiguous rows).
// Staging: unpadded 128x32 bf16 tiles (global_load_lds: wave-uniform base + lane*16).
#define TLD 136   // epilogue transpose-tile row (bf16): 272 B, 16 B-aligned
__global__ __launch_bounds__(256) void qkv_gemm(
    const unsigned short* __restrict__ xb,   // 4096 x 512
    const unsigned short* __restrict__ wb,   // 3 x (512 x 512), (N,K)
    const float* __restrict__ bq, const float* __restrict__ bk, const float* __restrict__ bv,
    unsigned short* __restrict__ q, unsigned short* __restrict__ k,
    unsigned short* __restrict__ vt)
{
    __shared__ __align__(16) char smem[34816];
    unsigned short* As = (unsigned short*)smem;            // 128*32*2 = 8192 B
    unsigned short* Bs = (unsigned short*)(smem + 8192);   // 8192 B
    unsigned short* Tl = (unsigned short*)smem;            // 34816 B (aliases after K-loop)

    const int t = threadIdx.x;
    const int w = t >> 6, l = t & 63;
    const int m0 = blockIdx.x * 128, n0 = blockIdx.y * 128, z = blockIdx.z;
    const unsigned short* W = wb + (size_t)z * 262144;
    const float* bias = (z == 0) ? bq : ((z == 1) ? bk : bv);

    floatx4 acc[4][4] = {};
    const int wm = (w >> 1) * 64, wn = (w & 1) * 64;
    const int fr = l & 15, fq = l >> 4, fk = fq * 8;

    // staging: instr s stages 16 rows (1 KB); lane l -> row +l/4, col (l&3)*8
    const unsigned short* gA = xb + (size_t)(m0 + w * 32 + (l >> 2)) * 512 + (l & 3) * 8;
    const unsigned short* gB = W  + (size_t)(n0 + w * 32 + (l >> 2)) * 512 + (l & 3) * 8;

    for (int kk = 0; kk < 512; kk += 32) {
#pragma unroll
        for (int s = 0; s < 2; s++) {
            gld16(gA + (size_t)s * 16 * 512 + kk, As + (w * 32 + s * 16) * 32);
            gld16(gB + (size_t)s * 16 * 512 + kk, Bs + (w * 32 + s * 16) * 32);
        }
        __syncthreads();
        short8 a[4], b[4];
#pragma unroll
        for (int i = 0; i < 4; i++) a[i] = *(const short8*)&As[(wm + i * 16 + fr) * 32 + fk];
#pragma unroll
        for (int j = 0; j < 4; j++) b[j] = *(const short8*)&Bs[(wn + j * 16 + fr) * 32 + fk];
#pragma unroll
        for (int i = 0; i < 4; i++)
#pragma unroll
            for (int j = 0; j < 4; j++)
                acc[i][j] = __builtin_amdgcn_mfma_f32_16x16x32_bf16(a[i], b[j], acc[i][j], 0, 0, 0);
        __syncthreads();
    }

    // epilogue: frags (C/D: col=lane&15, row=(lane>>4)*4+reg) -> LDS tile -> coalesced stores
    float bv_[4];
#pragma unroll
    for (int j = 0; j < 4; j++) bv_[j] = bias[n0 + wn + j * 16 + fr];

    if (z < 2) {
#pragma unroll
        for (int i = 0; i < 4; i++)
#pragma unroll
            for (int j = 0; j < 4; j++)
#pragma unroll
                for (int r = 0; r < 4; r++)
                    Tl[(wm + i * 16 + fq * 4 + r) * TLD + wn + j * 16 + fr] =
                        f2bf(acc[i][j][r] + bv_[j]);
    } else {
#pragma unroll
        for (int i = 0; i < 4; i++)
#pragma unroll
            for (int j = 0; j < 4; j++)
#pragma unroll
                for (int r = 0; r < 4; r++)
                    Tl[(wn + j * 16 + fr) * TLD + wm + i * 16 + fq * 4 + r] =
                        f2bf(acc[i][j][r] + bv_[j]);
    }
    __syncthreads();

    const int tl = t >> 1;
    unsigned short* out = (z == 0) ? q : ((z == 1) ? k : vt);
#pragma unroll
    for (int s = 0; s < 8; s++) {
        int c = (t & 1) * 64 + s * 8;
        uint4 val = *(const uint4*)&Tl[tl * TLD + c];
        if (z < 2)
            *(uint4*)&out[(size_t)(m0 + tl) * 512 + n0 + c] = val;
        else
            *(uint4*)&out[(size_t)(n0 + tl) * 4096 + m0 + c] = val;
    }
}

// ---------------- scores: S[16x16] per one-wave block, direct frag loads ----------------
// grid (128 Qtiles, 9 ntiles, 2 b), 64 threads. S fp32 [4096][160], cols 0..143 written.
__global__ __launch_bounds__(64) void scores_kernel(
    const unsigned short* __restrict__ qb, const unsigned short* __restrict__ kb,
    float* __restrict__ S)
{
    const int l = threadIdx.x;
    const int fr = l & 15, fq = l >> 4;
    const int Q0 = blockIdx.x * 16;
    const int nt = blockIdx.y;
    const int b  = blockIdx.z;
    const int R0 = Q0 - WIN;
    const int tok = R0 + nt * 16 + fr;
    const bool kvalid = (tok >= 0) && (tok < L_SEQ);

    const unsigned short* qrow = qb + (size_t)(b * L_SEQ + Q0 + fr) * 512 + fq * 8;
    const unsigned short* krow = kb + (size_t)(b * L_SEQ) * 512 + (size_t)tok * 512 + fq * 8;

    floatx4 acc = {};
#pragma unroll
    for (int ks = 0; ks < 16; ks++) {
        short8 a = *(const short8*)(qrow + ks * 32);
        short8 bfr = {};
        if (kvalid) bfr = *(const short8*)(krow + ks * 32);
        acc = __builtin_amdgcn_mfma_f32_16x16x32_bf16(a, bfr, acc, 0, 0, 0);
    }

    const int jg = nt * 16 + fr;
    float* Srow = S + (size_t)(b * L_SEQ + Q0) * 160 + jg;
#pragma unroll
    for (int r = 0; r < 4; r++) {
        int qq = fq * 4 + r;
        bool valid = (jg >= qq) && (jg <= qq + 128) && kvalid;
        Srow[(size_t)qq * 160] = valid ? acc[r] * SCALE_QK : -1e30f;
    }
}

// ---------------- softmax: one wave per row -> P bf16 [4096][160] ----------------
__global__ __launch_bounds__(256) void softmax_kernel(
    const float* __restrict__ S, unsigned short* __restrict__ P)
{
    const int t = threadIdx.x;
    const int row = blockIdx.x * 4 + (t >> 6);
    const int l = t & 63;
    const float* Sr = S + (size_t)row * 160;
    float s1 = Sr[l], s2 = Sr[64 + l];
    float s3 = (l < 16) ? Sr[128 + l] : -1e30f;
    float m = fmaxf(fmaxf(s1, s2), s3);
#pragma unroll
    for (int d = 32; d >= 1; d >>= 1) m = fmaxf(m, __shfl_xor(m, d));
    float e1 = __expf(s1 - m), e2 = __expf(s2 - m);
    float e3 = (l < 16) ? __expf(s3 - m) : 0.f;
    float sum = e1 + e2 + e3;
#pragma unroll
    for (int d = 32; d >= 1; d >>= 1) sum += __shfl_xor(sum, d);
    float inv = 1.f / sum;
    unsigned short* Pr = P + (size_t)row * 160;
    Pr[l] = f2bf(e1 * inv);
    Pr[64 + l] = f2bf(e2 * inv);
    if (l < 16) Pr[128 + l] = f2bf(e3 * inv);
    else if (l < 32) Pr[128 + l] = 0;   // zero K-pad cols 144..159
}

// ---------------- pv: out[16q x 32e] per one-wave block ----------------
// grid (128 Qtiles, 16 e-pairs, 2 b), 64 threads. P A-frags + vT B-frags direct from global.
__global__ __launch_bounds__(64) void pv_kernel(
    const unsigned short* __restrict__ P, const unsigned short* __restrict__ vt,
    float* __restrict__ out)
{
    const int l = threadIdx.x;
    const int fr = l & 15, fq = l >> 4;
    const int Q0 = blockIdx.x * 16;
    const int EC = blockIdx.y * 32;
    const int b  = blockIdx.z;
    const int R0 = Q0 - WIN;

    const unsigned short* Prow = P + (size_t)(b * L_SEQ + Q0 + fr) * 160 + fq * 8;

    floatx4 oa[2] = {};
#pragma unroll
    for (int ks = 0; ks < 5; ks++) {
        short8 a = *(const short8*)(Prow + ks * 32);
        int tok0 = R0 + ks * 32 + fq * 8;                 // mod-8 aligned granule
        bool tv = (tok0 >= 0) && (tok0 < L_SEQ);
#pragma unroll
        for (int et = 0; et < 2; et++) {
            short8 bfr = {};
            if (tv) bfr = *(const short8*)&vt[(size_t)(EC + et * 16 + fr) * 4096 + b * L_SEQ + tok0];
            oa[et] = __builtin_amdgcn_mfma_f32_16x16x32_bf16(a, bfr, oa[et], 0, 0, 0);
        }
    }

    float* op = out + (size_t)b * L_SEQ * E_DIM;
#pragma unroll
    for (int et = 0; et < 2; et++)
#pragma unroll
        for (int r = 0; r < 4; r++)
            op[(size_t)(Q0 + fq * 4 + r) * 512 + EC + et * 16 + fr] = oa[et][r];
}

// ---------------- launch ----------------
extern "C" void kernel_launch(void* const* d_in, const int* in_sizes, int n_in,
                              void* d_out, int out_size, void* d_ws, size_t ws_size,
                              hipStream_t stream)
{
    const float* x  = (const float*)d_in[0];
    const float* Wq = (const float*)d_in[1];
    const float* bq = (const float*)d_in[2];
    const float* Wk = (const float*)d_in[3];
    const float* bk = (const float*)d_in[4];
    const float* Wv = (const float*)d_in[5];
    const float* bv = (const float*)d_in[6];
    float* out = (float*)d_out;

    char* ws = (char*)d_ws;
    unsigned short* qb = (unsigned short*)(ws);                  // 4 MB bf16 q
    unsigned short* kb = (unsigned short*)(ws + 4194304);        // 4 MB bf16 k
    unsigned short* vt = (unsigned short*)(ws + 8388608);        // 4 MB bf16 v^T [e][tok]
    unsigned short* xb = (unsigned short*)(ws + 12582912);       // 4 MB bf16 x
    unsigned short* wb = (unsigned short*)(ws + 16777216);       // 1.5 MB bf16 W
    float*          S  = (float*)(ws + 18350080);                // 2.62 MB fp32 [4096][160]
    unsigned short* P  = (unsigned short*)(ws + 20971520);       // 1.31 MB bf16 [4096][160]

    cvt_kernel<<<2816, 256, 0, stream>>>(x, Wq, Wk, Wv, xb, wb);
    qkv_gemm<<<dim3(32, 4, 3), 256, 0, stream>>>(xb, wb, bq, bk, bv, qb, kb, vt);
    scores_kernel<<<dim3(128, 9, 2), 64, 0, stream>>>(qb, kb, S);
    softmax_kernel<<<1024, 256, 0, stream>>>(S, P);
    pv_kernel<<<dim3(128, 16, 2), 64, 0, stream>>>(P, vt, out);
}

// Round 5
// 112.004 us; speedup vs baseline: 2.0499x; 1.0394x over previous
//
#include <hip/hip_runtime.h>
#include <cstdint>
#include <cstddef>

#define L_SEQ 2048
#define E_DIM 512
#define B_SZ 2
#define WIN 64
#define SCALE_QK 0.044194173824159216f  // 1/sqrt(512)

typedef __attribute__((ext_vector_type(8))) short short8;
typedef __attribute__((ext_vector_type(4))) float floatx4;

__device__ __forceinline__ unsigned short f2bf(float f) {
    unsigned int u = __float_as_uint(f);
    u += 0x7FFFu + ((u >> 16) & 1u);
    return (unsigned short)(u >> 16);
}

// ---------------- fp32 -> bf16 conversion of x, Wq, Wk, Wv ----------------
__global__ __launch_bounds__(256) void cvt_kernel(
    const float* __restrict__ x, const float* __restrict__ wq,
    const float* __restrict__ wk, const float* __restrict__ wv,
    unsigned short* __restrict__ xb, unsigned short* __restrict__ wb)
{
    long i = (long)blockIdx.x * 256 + threadIdx.x;   // 0 .. 720895
    const float* src;
    unsigned short* dst;
    long off;
    if (i < 524288) {
        src = x; dst = xb; off = i;
    } else {
        long j = i - 524288;
        int w = (int)(j >> 16);
        off = j & 65535;
        src = (w == 0) ? wq : ((w == 1) ? wk : wv);
        dst = wb + (long)w * 262144;
    }
    float4 f = ((const float4*)src)[off];
    ushort4 o;
    o.x = f2bf(f.x); o.y = f2bf(f.y); o.z = f2bf(f.z); o.w = f2bf(f.w);
    ((ushort4*)dst)[off] = o;
}

// ---------------- QKV projection: 64x64 tile, BK=64, reg double-buffer ----------------
// C[m,n] = sum_k X[m,k] W[n,k] + bias[n].  Outputs bf16, coalesced via LDS transpose.
// z==0 -> q[m][n], z==1 -> k[m][n], z==2 -> vT[n][m] (token-contiguous rows).
// grid (64,8,3) = 1536 blocks = 6 blocks/CU (occupancy fix for the small-N shape).
#define ALD 72   // LDS row stride (bf16): 36 dw -> 2-way conflicts only per 16-lane phase
__global__ __launch_bounds__(256) void qkv_gemm(
    const unsigned short* __restrict__ xb,   // 4096 x 512
    const unsigned short* __restrict__ wb,   // 3 x (512 x 512), (N,K)
    const float* __restrict__ bq, const float* __restrict__ bk, const float* __restrict__ bv,
    unsigned short* __restrict__ q, unsigned short* __restrict__ k,
    unsigned short* __restrict__ vt)
{
    __shared__ __align__(16) unsigned short As[64 * ALD];   // 9216 B (aliased by epilogue)
    __shared__ __align__(16) unsigned short Bs[64 * ALD];

    const int t = threadIdx.x;
    const int w = t >> 6, l = t & 63;
    const int m0 = blockIdx.x * 64, n0 = blockIdx.y * 64, z = blockIdx.z;
    const unsigned short* W = wb + (size_t)z * 262144;
    const float* bias = (z == 0) ? bq : ((z == 1) ? bk : bv);

    floatx4 acc[2][2] = {};
    const int wm = (w >> 1) * 32, wn = (w & 1) * 32;
    const int fr = l & 15, fq = l >> 4, fk = fq * 8;

    const int srow = t >> 2, scol = (t & 3) * 16;
    const unsigned short* gA = xb + (size_t)(m0 + srow) * 512 + scol;
    const unsigned short* gB = W  + (size_t)(n0 + srow) * 512 + scol;

    uint4 ra0 = *(const uint4*)(gA);     uint4 ra1 = *(const uint4*)(gA + 8);
    uint4 rb0 = *(const uint4*)(gB);     uint4 rb1 = *(const uint4*)(gB + 8);

    for (int it = 0; it < 8; it++) {
        *(uint4*)&As[srow * ALD + scol]     = ra0;
        *(uint4*)&As[srow * ALD + scol + 8] = ra1;
        *(uint4*)&Bs[srow * ALD + scol]     = rb0;
        *(uint4*)&Bs[srow * ALD + scol + 8] = rb1;
        __syncthreads();
        if (it < 7) {                       // prefetch next K-slice; overlaps compute below
            int kk = (it + 1) * 64;
            ra0 = *(const uint4*)(gA + kk); ra1 = *(const uint4*)(gA + kk + 8);
            rb0 = *(const uint4*)(gB + kk); rb1 = *(const uint4*)(gB + kk + 8);
        }
        short8 a[2][2], bf[2][2];
#pragma unroll
        for (int i = 0; i < 2; i++)
#pragma unroll
            for (int kh = 0; kh < 2; kh++)
                a[i][kh] = *(const short8*)&As[(wm + i * 16 + fr) * ALD + kh * 32 + fk];
#pragma unroll
        for (int j = 0; j < 2; j++)
#pragma unroll
            for (int kh = 0; kh < 2; kh++)
                bf[j][kh] = *(const short8*)&Bs[(wn + j * 16 + fr) * ALD + kh * 32 + fk];
#pragma unroll
        for (int kh = 0; kh < 2; kh++)
#pragma unroll
            for (int i = 0; i < 2; i++)
#pragma unroll
                for (int j = 0; j < 2; j++)
                    acc[i][j] = __builtin_amdgcn_mfma_f32_16x16x32_bf16(a[i][kh], bf[j][kh], acc[i][j], 0, 0, 0);
        __syncthreads();
    }

    // epilogue: frags (C/D: col=lane&15, row=(lane>>4)*4+reg) -> LDS tile -> coalesced stores
    unsigned short* Tl = As;   // 64 x ALD alias
    float bv_[2];
#pragma unroll
    for (int j = 0; j < 2; j++) bv_[j] = bias[n0 + wn + j * 16 + fr];

    if (z < 2) {
#pragma unroll
        for (int i = 0; i < 2; i++)
#pragma unroll
            for (int j = 0; j < 2; j++)
#pragma unroll
                for (int r = 0; r < 4; r++)
                    Tl[(wm + i * 16 + fq * 4 + r) * ALD + wn + j * 16 + fr] =
                        f2bf(acc[i][j][r] + bv_[j]);
    } else {
#pragma unroll
        for (int i = 0; i < 2; i++)
#pragma unroll
            for (int j = 0; j < 2; j++)
#pragma unroll
                for (int r = 0; r < 4; r++)
                    Tl[(wn + j * 16 + fr) * ALD + wm + i * 16 + fq * 4 + r] =
                        f2bf(acc[i][j][r] + bv_[j]);
    }
    __syncthreads();

    const int tr = t >> 2, tc = (t & 3) * 16;
    uint4 v0 = *(const uint4*)&Tl[tr * ALD + tc];
    uint4 v1 = *(const uint4*)&Tl[tr * ALD + tc + 8];
    if (z < 2) {
        unsigned short* out = (z == 0) ? q : k;
        *(uint4*)&out[(size_t)(m0 + tr) * 512 + n0 + tc]     = v0;
        *(uint4*)&out[(size_t)(m0 + tr) * 512 + n0 + tc + 8] = v1;
    } else {
        *(uint4*)&vt[(size_t)(n0 + tr) * 4096 + m0 + tc]     = v0;
        *(uint4*)&vt[(size_t)(n0 + tr) * 4096 + m0 + tc + 8] = v1;
    }
}

// ---------------- scores: S[16x16] per one-wave block, direct frag loads ----------------
// grid (128 Qtiles, 9 ntiles, 2 b), 64 threads. S fp32 [4096][160], cols 0..143 written.
__global__ __launch_bounds__(64) void scores_kernel(
    const unsigned short* __restrict__ qb, const unsigned short* __restrict__ kb,
    float* __restrict__ S)
{
    const int l = threadIdx.x;
    const int fr = l & 15, fq = l >> 4;
    const int Q0 = blockIdx.x * 16;
    const int nt = blockIdx.y;
    const int b  = blockIdx.z;
    const int R0 = Q0 - WIN;
    const int tok = R0 + nt * 16 + fr;
    const bool kvalid = (tok >= 0) && (tok < L_SEQ);

    const unsigned short* qrow = qb + (size_t)(b * L_SEQ + Q0 + fr) * 512 + fq * 8;
    const unsigned short* krow = kb + (size_t)(b * L_SEQ) * 512 + (size_t)tok * 512 + fq * 8;

    floatx4 acc = {};
#pragma unroll
    for (int ks = 0; ks < 16; ks++) {
        short8 a = *(const short8*)(qrow + ks * 32);
        short8 bfr = {};
        if (kvalid) bfr = *(const short8*)(krow + ks * 32);
        acc = __builtin_amdgcn_mfma_f32_16x16x32_bf16(a, bfr, acc, 0, 0, 0);
    }

    const int jg = nt * 16 + fr;
    float* Srow = S + (size_t)(b * L_SEQ + Q0) * 160 + jg;
#pragma unroll
    for (int r = 0; r < 4; r++) {
        int qq = fq * 4 + r;
        bool valid = (jg >= qq) && (jg <= qq + 128) && kvalid;
        Srow[(size_t)qq * 160] = valid ? acc[r] * SCALE_QK : -1e30f;
    }
}

// ---------------- pv (fused softmax): out[16q x 32e] per one-wave block ----------------
// grid (128 Qtiles, 16 e-pairs, 2 b), 64 threads. Reads raw S, computes softmax
// in-register (4 lanes per q-row via shfl_xor 16/32), builds bf16 A-frags, MFMA vs vT.
__global__ __launch_bounds__(64) void pv_kernel(
    const float* __restrict__ S, const unsigned short* __restrict__ vt,
    float* __restrict__ out)
{
    const int l = threadIdx.x;
    const int fr = l & 15, fq = l >> 4;
    const int Q0 = blockIdx.x * 16;
    const int EC = blockIdx.y * 32;
    const int b  = blockIdx.z;
    const int R0 = Q0 - WIN;

    // lane covers S row (Q0+fr), cols fq*8 + ks*32 + j  (ks<5, j<8)
    const float* Srow = S + (size_t)(b * L_SEQ + Q0 + fr) * 160 + fq * 8;
    float sv[5][8];
#pragma unroll
    for (int ks = 0; ks < 5; ks++) {
        float4 u0 = *(const float4*)(Srow + ks * 32);
        float4 u1 = *(const float4*)(Srow + ks * 32 + 4);
        sv[ks][0] = u0.x; sv[ks][1] = u0.y; sv[ks][2] = u0.z; sv[ks][3] = u0.w;
        sv[ks][4] = u1.x; sv[ks][5] = u1.y; sv[ks][6] = u1.z; sv[ks][7] = u1.w;
    }
    if (fq >= 2) {                    // cols 144..159: unwritten pad
#pragma unroll
        for (int j = 0; j < 8; j++) sv[4][j] = -1e30f;
    }
    float m = -1e30f;
#pragma unroll
    for (int ks = 0; ks < 5; ks++)
#pragma unroll
        for (int j = 0; j < 8; j++) m = fmaxf(m, sv[ks][j]);
    m = fmaxf(m, __shfl_xor(m, 16));
    m = fmaxf(m, __shfl_xor(m, 32));
    float sum = 0.f;
#pragma unroll
    for (int ks = 0; ks < 5; ks++)
#pragma unroll
        for (int j = 0; j < 8; j++) { float e = __expf(sv[ks][j] - m); sv[ks][j] = e; sum += e; }
    sum += __shfl_xor(sum, 16);
    sum += __shfl_xor(sum, 32);
    float inv = 1.f / sum;

    short8 a[5];
#pragma unroll
    for (int ks = 0; ks < 5; ks++)
#pragma unroll
        for (int j = 0; j < 8; j++) a[ks][j] = (short)f2bf(sv[ks][j] * inv);

    floatx4 oa[2] = {};
#pragma unroll
    for (int ks = 0; ks < 5; ks++) {
        int tok0 = R0 + ks * 32 + fq * 8;                 // mod-8 aligned granule
        bool tv = (tok0 >= 0) && (tok0 < L_SEQ);
#pragma unroll
        for (int et = 0; et < 2; et++) {
            short8 bfr = {};
            if (tv) bfr = *(const short8*)&vt[(size_t)(EC + et * 16 + fr) * 4096 + b * L_SEQ + tok0];
            oa[et] = __builtin_amdgcn_mfma_f32_16x16x32_bf16(a[ks], bfr, oa[et], 0, 0, 0);
        }
    }

    float* op = out + (size_t)b * L_SEQ * E_DIM;
#pragma unroll
    for (int et = 0; et < 2; et++)
#pragma unroll
        for (int r = 0; r < 4; r++)
            op[(size_t)(Q0 + fq * 4 + r) * 512 + EC + et * 16 + fr] = oa[et][r];
}

// ---------------- launch ----------------
extern "C" void kernel_launch(void* const* d_in, const int* in_sizes, int n_in,
                              void* d_out, int out_size, void* d_ws, size_t ws_size,
                              hipStream_t stream)
{
    const float* x  = (const float*)d_in[0];
    const float* Wq = (const float*)d_in[1];
    const float* bq = (const float*)d_in[2];
    const float* Wk = (const float*)d_in[3];
    const float* bk = (const float*)d_in[4];
    const float* Wv = (const float*)d_in[5];
    const float* bv = (const float*)d_in[6];
    float* out = (float*)d_out;

    char* ws = (char*)d_ws;
    unsigned short* qb = (unsigned short*)(ws);                  // 4 MB bf16 q
    unsigned short* kb = (unsigned short*)(ws + 4194304);        // 4 MB bf16 k
    unsigned short* vt = (unsigned short*)(ws + 8388608);        // 4 MB bf16 v^T [e][tok]
    unsigned short* xb = (unsigned short*)(ws + 12582912);       // 4 MB bf16 x
    unsigned short* wb = (unsigned short*)(ws + 16777216);       // 1.5 MB bf16 W
    float*          S  = (float*)(ws + 18350080);                // 2.62 MB fp32 [4096][160]

    cvt_kernel<<<2816, 256, 0, stream>>>(x, Wq, Wk, Wv, xb, wb);
    qkv_gemm<<<dim3(64, 8, 3), 256, 0, stream>>>(xb, wb, bq, bk, bv, qb, kb, vt);
    scores_kernel<<<dim3(128, 9, 2), 64, 0, stream>>>(qb, kb, S);
    pv_kernel<<<dim3(128, 16, 2), 64, 0, stream>>>(S, vt, out);
}